// Round 13
// baseline (1066.997 us; speedup 1.0000x reference)
//
#include <hip/hip_runtime.h>
#include <hip/hip_cooperative_groups.h>

namespace cg = cooperative_groups;

// GCN 4-layer, linear network => collapse to:
// out = A^4 x0 * c4 + A^3 1 * c3 + A^2 1 * c2 + A 1 * c1 + b4,
// A = D^-1/2 (Adj+I) D^-1/2. Propagate in scaled space u' = D^-1 (Adj+I) u,
// epilogue multiplies sqrt(deg). Channels (x-path, ones-path) packed float2.
// Dtypes (R1-R4 verified): read_length int32, edge_index int32, W/b fp32, out fp32.
//
// R20: (a) REVERT R19's 4-window unroll (VGPR_Count stayed 12 -> compiler
// re-serialized it; 392 vs 383us). (b) Fuse the 4 sweeps into ONE
// cooperative kernel (489 blocks x 1024, 8KB LDS, launch_bounds(1024,8)
// -> 2 blocks/CU, 512 >= 489 co-resident): sum-of-parts says ~60us of the
// 383 is launch gaps + drains; and per-XCD-pinned blocks make each XCD's
// ~4MB epart2 share L2-resident across sweeps 2-4 (saves ~70MB HBM).
// __threadfence() before each grid.sync() for cross-XCD visibility.
// (c) probe merged into scatter (block PB); cur zeroed via hipMemsetAsync.
// Runtime fallback: if hipLaunchCooperativeKernel errors, enqueue the R18
// split path (kernels kept below).

#define BLK  256
#define SBLK 1024         // scatter block
#define NB   512          // buckets
#define BSH  10           // bucket = dst >> 10  (1024 nodes / bucket)
#define PB   512          // partition blocks
#define BUFCAP 15872      // scatter LDS sort buffer (chunk = ceil(8M/512) = 15625)
#define BUF2 17920        // csr LDS buffer (bucket mean 16384, sd ~128; +12 sigma)
#define CAP  18432        // epart segment capacity per bucket (mean + 16 sigma)

// single-pass scatter: block-local LDS counting sort by bucket, one global
// atomicAdd per bucket run reserves space in the bucket's CAP segment; runs
// copied out dense+coalesced. Block PB = int64-layout probe (if rl were
// int64, every odd word is 0) writing flag.
__global__ __launch_bounds__(SBLK)
void scatter(const int* __restrict__ src, const int* __restrict__ dst,
             int* __restrict__ cur, unsigned* __restrict__ epart, int E,
             const int* __restrict__ rl32, int* __restrict__ flag) {
    __shared__ unsigned buf[BUFCAP];     // 62 KB
    __shared__ int h[NB];                // per-chunk counts
    __shared__ int c0[NB];               // fill cursor (exclusive starts)
    __shared__ int gpos[NB];             // reserved global position
    __shared__ int wsum[16];             // wave totals for scan
    int j = blockIdx.x, t = threadIdx.x;
    int lane = t & 63, w = t >> 6;
    if (j == PB) {                       // probe block
        int acc = rl32[2 * t + 1];
#pragma unroll
        for (int off = 1; off < 64; off <<= 1) acc |= __shfl_xor(acc, off);
        if (lane == 0) h[w] = acc;
        __syncthreads();
        if (t == 0) {
            int a = 0;
            for (int i = 0; i < 16; ++i) a |= h[i];
            *flag = (a != 0) ? 1 : 0;    // 1 => int32 layout
        }
        return;
    }
    int chunk = (E + PB - 1) / PB;
    int beg = j * chunk, end = min(beg + chunk, E);
    for (int s = beg; s < end; s += BUFCAP) {
        int se = min(s + BUFCAP, end);
        for (int b = t; b < NB; b += SBLK) h[b] = 0;
        __syncthreads();
        for (int e = s + t; e < se; e += SBLK)
            atomicAdd(&h[((unsigned)dst[e]) >> BSH], 1);
        __syncthreads();
        // hierarchical exclusive scan of h into c0 (512 entries, 8 waves)
        if (t < NB) {
            int v = h[t];
            int run = v;
#pragma unroll
            for (int off = 1; off < 64; off <<= 1) {
                int u = __shfl_up(run, off);
                if (lane >= off) run += u;
            }
            if (lane == 63) wsum[w] = run;
            c0[t] = run - v;             // intra-wave exclusive
        }
        __syncthreads();
        if (t < 8) {                     // scan 8 wave totals (one wave)
            int v = wsum[t];
            int run = v;
#pragma unroll
            for (int off = 1; off < 8; off <<= 1) {
                int u = __shfl_up(run, off, 8);
                if ((t & 7) >= off) run += u;
            }
            wsum[t] = run - v;           // exclusive wave offsets
        }
        __syncthreads();
        if (t < NB) c0[t] += wsum[w];
        __syncthreads();
        // fill LDS buffer sorted by bucket
        for (int e = s + t; e < se; e += SBLK) {
            unsigned d = (unsigned)dst[e];
            int b = d >> BSH;
            int slot = atomicAdd(&c0[b], 1);
            buf[slot] = ((d & 1023u) << 19) | (unsigned)src[e];
        }
        __syncthreads();
        // reserve global space: one thread per bucket
        if (t < NB) {
            int n = h[t];
            gpos[t] = (n > 0) ? atomicAdd(&cur[t], n) : 0;
        }
        __syncthreads();
        // copy out: wave w handles buckets w, w+16, ... (runs contiguous)
        for (int b = w; b < NB; b += (SBLK >> 6)) {
            int n = h[b];
            int lo = c0[b] - n;          // c0 back to inclusive after fill
            int gp = gpos[b];
            int left = CAP - gp;         // overflow guard (unreachable)
            if (left < 0) left = 0;
            if (n > left) n = left;
            unsigned gb = (unsigned)b * CAP + (unsigned)gp;
            for (int k = lane; k < n; k += 64)
                epart[gb + k] = buf[lo + k];
        }
        __syncthreads();
    }
}

// per-bucket dst-sort (keeps full pack) + compact write + bstart; node init
// fused (degree = pre-scan count); coeffs in the last block.
// seg=0: compact epart2 (disjoint). seg=1: sorted in place in the segment.
__global__ __launch_bounds__(1024)
void csr_init(const unsigned* __restrict__ epart, const int* __restrict__ cur,
              const int* __restrict__ rl, const int* __restrict__ flag,
              unsigned* __restrict__ epart2, int* __restrict__ bstart,
              float* __restrict__ dinv, float2* __restrict__ v0, int N,
              const float* __restrict__ W1, const float* __restrict__ b1,
              const float* __restrict__ W2, const float* __restrict__ b2,
              const float* __restrict__ W3, const float* __restrict__ b3,
              const float* __restrict__ W4, const float* __restrict__ b4,
              float* __restrict__ c, int seg) {
    __shared__ unsigned buf[BUF2];     // 70 KB
    __shared__ int sc[1024];           // histogram counts
    __shared__ int cu[1024];           // fill cursors (exclusive starts)
    __shared__ int wsum[16];
    __shared__ int s_beg, s_n;
    int b = blockIdx.x, t = threadIdx.x;
    if (b == gridDim.x - 1) {
        // coeffs block
        __shared__ float p3[16], q3[16], r3[16];
        if (t == 0) {
            float p2[8], q2[8];
            for (int j = 0; j < 8; ++j) {
                float s1 = 0.f, s2 = 0.f;
                for (int k = 0; k < 4; ++k) {
                    float w = W2[k * 8 + j];
                    s1 += W1[k] * w;
                    s2 += b1[k] * w;
                }
                p2[j] = s1; q2[j] = s2;
            }
            for (int m = 0; m < 16; ++m) {
                float s1 = 0.f, s2 = 0.f, s3 = 0.f;
                for (int j = 0; j < 8; ++j) {
                    float w = W3[j * 16 + m];
                    s1 += p2[j] * w; s2 += q2[j] * w;
                    s3 += b2[j] * w;
                }
                p3[m] = s1; q3[m] = s2; r3[m] = s3;
            }
        }
        __syncthreads();
        if (t < 32) {
            float c4 = 0.f, c3 = 0.f, c2 = 0.f, c1 = 0.f;
            for (int k = 0; k < 16; ++k) {
                float w = W4[k * 32 + t];
                c4 += p3[k] * w; c3 += q3[k] * w; c2 += r3[k] * w;
                c1 += b3[k] * w;
            }
            c[t] = c4; c[32 + t] = c3; c[64 + t] = c2; c[96 + t] = c1;
        }
        return;
    }
    int lane = t & 63, w = t >> 6;
    if (t < 64) {
        int pre = 0, nn = 0;
        for (int k = t; k < NB; k += 64) {
            int v = min(cur[k], CAP);
            if (k < b) pre += v;
            if (k == b) nn = v;
        }
        for (int off = 1; off < 64; off <<= 1) {
            pre += __shfl_xor(pre, off);
            nn  += __shfl_xor(nn, off);
        }
        if (t == 0) { s_beg = pre; s_n = nn; }
    }
    sc[t] = 0;
    __syncthreads();
    int n = s_n;
    int gseg = b * CAP;
    int beg = seg ? gseg : s_beg;
    if (t == 0) bstart[b] = beg;
    if (b == gridDim.x - 2 && t == 1) bstart[b + 1] = beg + n;
    for (int e = t; e < n; e += 1024)
        atomicAdd(&sc[epart[gseg + e] >> 19], 1);
    __syncthreads();
    // hierarchical inclusive scan of sc (1024 entries, 16 waves)
    int v = sc[t];
    int run = v;
#pragma unroll
    for (int off = 1; off < 64; off <<= 1) {
        int u = __shfl_up(run, off);
        if (lane >= off) run += u;
    }
    if (lane == 63) wsum[w] = run;
    __syncthreads();
    if (t < 16) {
        int vv = wsum[t];
        int r2 = vv;
#pragma unroll
        for (int off = 1; off < 16; off <<= 1) {
            int u = __shfl_up(r2, off, 16);
            if ((t & 15) >= off) r2 += u;
        }
        wsum[t] = r2 - vv;               // exclusive wave offsets
    }
    __syncthreads();
    int incl = run + wsum[w];            // inclusive prefix incl. own count
    int start = incl - v;                // exclusive, bucket-local slot
    cu[t] = start;
    // fused node init: degree = v (own count)
    int gi = (b << 10) + t;
    if (gi < N) {
        int rv = (*flag) ? rl[gi] : rl[2 * gi];
        float d = (float)v + 1.0f;       // + self-loop
        dinv[gi] = 1.0f / d;
        float rs = rsqrtf(d);
        float2 u; u.x = rs * ((float)rv * (1.0f / 20000.0f)); u.y = rs;
        v0[gi] = u;
    }
    __syncthreads();
    if (n <= BUF2) {
        for (int e = t; e < n; e += 1024) {
            unsigned p = epart[gseg + e];
            int slot = atomicAdd(&cu[p >> 19], 1);
            buf[slot] = p;               // FULL pack (dst|src) kept
        }
        __syncthreads();
        for (int k = t; k < n; k += 1024)
            epart2[beg + k] = buf[k];    // dense coalesced write-out
    } else if (!seg) {
        for (int e = t; e < n; e += 1024) {
            unsigned p = epart[gseg + e];
            int slot = atomicAdd(&cu[p >> 19], 1);
            epart2[beg + slot] = p;
        }
    }
    // seg && n>BUF2: unreachable (P ~ 1e-33).
}

// one x+y sweep over a bucket: coalesced edge load + wave-gather + row-16
// DPP segmented scan + LDS atomicAdd at row-tails / key-changes.
__device__ __forceinline__ void sweep_xy(const unsigned* __restrict__ ep,
    int beg, int end, int t, int lane, int sub, int gi, int N,
    const float2* __restrict__ vin, float2* __restrict__ vout,
    const float* __restrict__ dinv, float* __restrict__ zsave,
    float* ax, float* ay) {
    ax[t] = 0.f; ay[t] = 0.f;
    __syncthreads();
    for (int base = beg + (t - lane); base < end; base += 1024) {
        int e = base + lane;
        unsigned p = (e < end) ? ep[e] : 0xFFFFFFFFu;  // sentinel key 8191
        int key = (int)(p >> 19);
        float vx = 0.f, vy = 0.f;
        if (e < end) {
            float2 u = vin[p & 0x7FFFFu];
            vx = u.x; vy = u.y;
        }
#pragma unroll
        for (int off = 1; off < 16; off <<= 1) {       // row-16 DPP scan
            float ox = __shfl_up(vx, off, 16);
            float oy = __shfl_up(vy, off, 16);
            int ok = __shfl_up(key, off, 16);
            bool act = (sub >= off) && (ok == key);
            vx += act ? ox : 0.f;
            vy += act ? oy : 0.f;
        }
        int nk = __shfl_down(key, 1);
        bool tail = (sub == 15) || (lane == 63) || (nk != key);
        if (tail && key < 1024) {
            atomicAdd(&ax[key], vx);
            atomicAdd(&ay[key], vy);
        }
    }
    __syncthreads();
    if (gi < N) {
        float2 self = vin[gi];
        float di = dinv[gi];
        float2 o; o.x = (ax[t] + self.x) * di; o.y = (ay[t] + self.y) * di;
        vout[gi] = o;
        zsave[gi] = o.y;
    }
}

// R20: all 4 sweeps + epilogue in ONE cooperative kernel. Blocks stay
// pinned to their CU/XCD -> epart2 slice L2-resident across sweeps; 3 launch
// boundaries removed. grid.sync() between sweeps (+threadfence for cross-XCD
// visibility). Valid only on the fits path (compact epart2 in workspace).
__global__ __launch_bounds__(1024, 8)
void sweeps_coop(const unsigned* __restrict__ ep, const int* __restrict__ bstart,
                 float2* __restrict__ v0, float2* __restrict__ v1,
                 const float* __restrict__ dinv,
                 float* __restrict__ z1, float* __restrict__ z2,
                 float* __restrict__ z3, const float* __restrict__ c,
                 const float* __restrict__ b4, float* __restrict__ out, int N) {
    __shared__ float ax[1024];
    __shared__ float ay[1024];
    cg::grid_group grid = cg::this_grid();
    int b = blockIdx.x, t = threadIdx.x;
    int lane = t & 63, sub = lane & 15;
    int beg = bstart[b], end = bstart[b + 1];
    int gi = (b << 10) + t;
    sweep_xy(ep, beg, end, t, lane, sub, gi, N, v0, v1, dinv, z1, ax, ay);
    __threadfence(); grid.sync();
    sweep_xy(ep, beg, end, t, lane, sub, gi, N, v1, v0, dinv, z2, ax, ay);
    __threadfence(); grid.sync();
    sweep_xy(ep, beg, end, t, lane, sub, gi, N, v0, v1, dinv, z3, ax, ay);
    __threadfence(); grid.sync();
    // final sweep (x only) + epilogue
    ax[t] = 0.f;
    __syncthreads();
    for (int base = beg + (t - lane); base < end; base += 1024) {
        int e = base + lane;
        unsigned p = (e < end) ? ep[e] : 0xFFFFFFFFu;
        int key = (int)(p >> 19);
        float vx = 0.f;
        if (e < end) vx = v1[p & 0x7FFFFu].x;
#pragma unroll
        for (int off = 1; off < 16; off <<= 1) {       // row-16 DPP scan
            float ox = __shfl_up(vx, off, 16);
            int ok = __shfl_up(key, off, 16);
            bool act = (sub >= off) && (ok == key);
            vx += act ? ox : 0.f;
        }
        int nk = __shfl_down(key, 1);
        bool tail = (sub == 15) || (lane == 63) || (nk != key);
        if (tail && key < 1024) atomicAdd(&ax[key], vx);
    }
    __syncthreads();
    float ox = 0.f, sq = 0.f;
    if (gi < N) {
        float di = dinv[gi];
        ox = (ax[t] + v1[gi].x) * di;    // final A^4 x (scaled space)
        sq = rsqrtf(di);                 // = sqrt(deg)
    }
    __syncthreads();
    ax[t] = ox; ay[t] = sq;              // own slot only
    __syncthreads();
    // channel-parallel epilogue
    int f = t & 31, half = t >> 5;       // half in [0,32)
    float c4 = c[f], c3 = c[32 + f], c2 = c[64 + f], c1 = c[96 + f], bb = b4[f];
    int base_node = b << 10;
    for (int p = 0; p < 32; ++p) {
        int ln = p * 32 + half;
        int g = base_node + ln;
        if (g < N) {
            float zz1 = z1[g], zz2 = z2[g], zz3 = z3[g];
            float val = ay[ln] * (ax[ln] * c4 + zz3 * c3 + zz2 * c2 + zz1 * c1) + bb;
            out[(size_t)g * 32 + f] = val;
        }
    }
}

// ---- fallback kernels (split path / coop-launch failure) ----

__global__ __launch_bounds__(1024)
void gather_seg(const unsigned* __restrict__ ep, const int* __restrict__ bstart,
                const int* __restrict__ cur, int seg,
                const float2* __restrict__ vin, float2* __restrict__ vout,
                const float* __restrict__ dinv, float* __restrict__ zsave, int N) {
    __shared__ float ax[1024];
    __shared__ float ay[1024];
    int b = blockIdx.x, t = threadIdx.x;
    ax[t] = 0.f; ay[t] = 0.f;
    __syncthreads();
    int beg = bstart[b];
    int n = seg ? min(cur[b], CAP) : (bstart[b + 1] - beg);
    int end = beg + n;
    int lane = t & 63, sub = lane & 15;
    for (int base = beg + (t - lane); base < end; base += 1024) {
        int e = base + lane;
        unsigned p = (e < end) ? ep[e] : 0xFFFFFFFFu;
        int key = (int)(p >> 19);
        float vx = 0.f, vy = 0.f;
        if (e < end) {
            float2 u = vin[p & 0x7FFFFu];
            vx = u.x; vy = u.y;
        }
#pragma unroll
        for (int off = 1; off < 16; off <<= 1) {
            float ox = __shfl_up(vx, off, 16);
            float oy = __shfl_up(vy, off, 16);
            int ok = __shfl_up(key, off, 16);
            bool act = (sub >= off) && (ok == key);
            vx += act ? ox : 0.f;
            vy += act ? oy : 0.f;
        }
        int nk = __shfl_down(key, 1);
        bool tail = (sub == 15) || (lane == 63) || (nk != key);
        if (tail && key < 1024) {
            atomicAdd(&ax[key], vx);
            atomicAdd(&ay[key], vy);
        }
    }
    __syncthreads();
    int gi = (b << 10) + t;
    if (gi < N) {
        float2 self = vin[gi];
        float di = dinv[gi];
        float2 o; o.x = (ax[t] + self.x) * di; o.y = (ay[t] + self.y) * di;
        vout[gi] = o;
        if (zsave) zsave[gi] = o.y;
    }
}

__global__ __launch_bounds__(1024)
void gather_out_seg(const unsigned* __restrict__ ep, const int* __restrict__ bstart,
                    const float2* __restrict__ vin, const float* __restrict__ dinv,
                    const float* __restrict__ z1, const float* __restrict__ z2,
                    const float* __restrict__ z3, const float* __restrict__ c,
                    const float* __restrict__ b4, float* __restrict__ out, int N) {
    __shared__ float ax[1024];
    __shared__ float sqs[1024];
    int b = blockIdx.x, t = threadIdx.x;
    ax[t] = 0.f;
    __syncthreads();
    int beg = bstart[b], end = bstart[b + 1];
    int lane = t & 63, sub = lane & 15;
    for (int base = beg + (t - lane); base < end; base += 1024) {
        int e = base + lane;
        unsigned p = (e < end) ? ep[e] : 0xFFFFFFFFu;
        int key = (int)(p >> 19);
        float vx = 0.f;
        if (e < end) vx = vin[p & 0x7FFFFu].x;
#pragma unroll
        for (int off = 1; off < 16; off <<= 1) {
            float ox = __shfl_up(vx, off, 16);
            int ok = __shfl_up(key, off, 16);
            bool act = (sub >= off) && (ok == key);
            vx += act ? ox : 0.f;
        }
        int nk = __shfl_down(key, 1);
        bool tail = (sub == 15) || (lane == 63) || (nk != key);
        if (tail && key < 1024) atomicAdd(&ax[key], vx);
    }
    __syncthreads();
    int gi = (b << 10) + t;
    float ox = 0.f, sq = 0.f;
    if (gi < N) {
        float di = dinv[gi];
        ox = (ax[t] + vin[gi].x) * di;
        sq = rsqrtf(di);
    }
    __syncthreads();
    ax[t] = ox; sqs[t] = sq;
    __syncthreads();
    int f = t & 31, half = t >> 5;
    float c4 = c[f], c3 = c[32 + f], c2 = c[64 + f], c1 = c[96 + f], bb = b4[f];
    int base_node = b << 10;
    for (int p = 0; p < 32; ++p) {
        int ln = p * 32 + half;
        int g = base_node + ln;
        if (g < N) {
            float zz1 = z1[g], zz2 = z2[g], zz3 = z3[g];
            float val = sqs[ln] * (ax[ln] * c4 + zz3 * c3 + zz2 * c2 + zz1 * c1) + bb;
            out[(size_t)g * 32 + f] = val;
        }
    }
}

__global__ void write_out(const float2* __restrict__ v0, const float* __restrict__ z1,
                          const float* __restrict__ z2, const float* __restrict__ z3,
                          const float* __restrict__ dinv, const float* __restrict__ c,
                          const float* __restrict__ b4,
                          float* __restrict__ out, int N) {
    int t = blockIdx.x * blockDim.x + threadIdx.x;
    int i = t >> 5, f = t & 31;
    if (i < N) {
        float sq = rsqrtf(dinv[i]);  // = sqrt(deg)
        float v = sq * (v0[i].x * c[f] + z3[i] * c[32 + f] + z2[i] * c[64 + f]
                        + z1[i] * c[96 + f])
                  + b4[f];
        out[(size_t)i * 32 + f] = v;
    }
}

extern "C" void kernel_launch(void* const* d_in, const int* in_sizes, int n_in,
                              void* d_out, int out_size, void* d_ws, size_t ws_size,
                              hipStream_t stream) {
    const int N = in_sizes[0];
    const int E = in_sizes[1] / 2;
    const int* rl  = (const int*)d_in[0];
    const int* src = (const int*)d_in[1];
    const int* dst = src + E;
    const float* W1 = (const float*)d_in[2];
    const float* b1 = (const float*)d_in[3];
    const float* W2 = (const float*)d_in[4];
    const float* b2 = (const float*)d_in[5];
    const float* W3 = (const float*)d_in[6];
    const float* b3 = (const float*)d_in[7];
    const float* W4 = (const float*)d_in[8];
    const float* b4 = (const float*)d_in[9];

    const int gbNode = (N + 1023) / 1024;     // buckets containing nodes (489)

    // workspace layout
    char* w = (char*)d_ws;
    float2* v0   = (float2*)w;                w += (size_t)N * 8;
    float2* v1   = (float2*)w;                w += (size_t)N * 8;
    float*  dinv = (float*)w;                 w += (size_t)N * 4;
    float*  z1   = (float*)w;                 w += (size_t)N * 4;
    float*  z2   = (float*)w;                 w += (size_t)N * 4;
    float*  z3   = (float*)w;                 w += (size_t)N * 4;
    int*    bstart = (int*)w;                 w += (NB + 1) * 4;
    int*    cur  = (int*)w;                   w += NB * 4;
    float*  c    = (float*)w;                 w += 128 * 4;
    int*    flag = (int*)w;                   w += 16;
    // epart2 (compact, dst-sorted) in workspace if it fits
    size_t used = (size_t)(w - (char*)d_ws);
    used = (used + 255) & ~(size_t)255;
    bool fits = (used + (size_t)E * 4) <= ws_size;
    // segmented epart always lives in d_out (NB*CAP*4 = 37.75 MB <= 64 MB)
    unsigned* epart  = (unsigned*)d_out;
    unsigned* epart2 = fits ? (unsigned*)((char*)d_ws + used) : epart;  // in-place if !fits
    const int seg = fits ? 0 : 1;

    hipMemsetAsync(cur, 0, NB * sizeof(int), stream);

    // single-pass radix partition by dst bucket (+ probe block PB)
    scatter<<<PB + 1, SBLK, 0, stream>>>(src, dst, cur, epart, E, rl, flag);

    // within-bucket dst-sort + bstart + fused node init + coeffs
    csr_init<<<gbNode + 1, 1024, 0, stream>>>(epart, cur, rl, flag, epart2, bstart,
                                              dinv, v0, N,
                                              W1, b1, W2, b2, W3, b3, W4, b4, c, seg);

    bool done = false;
    if (fits) {
        float* outp = (float*)d_out;
        int Nv = N;
        void* args[] = { (void*)&epart2, (void*)&bstart, (void*)&v0, (void*)&v1,
                         (void*)&dinv, (void*)&z1, (void*)&z2, (void*)&z3,
                         (void*)&c, (void*)&b4, (void*)&outp, (void*)&Nv };
        hipError_t err = hipLaunchCooperativeKernel((void*)sweeps_coop,
                                                    dim3(gbNode), dim3(1024),
                                                    args, 0, stream);
        if (err == hipSuccess) {
            done = true;
        } else {
            (void)hipGetLastError();     // clear error state
        }
    }
    if (!done) {
        // split path (non-cooperative)
        gather_seg<<<gbNode, 1024, 0, stream>>>(epart2, bstart, cur, seg, v0, v1, dinv, z1, N);
        gather_seg<<<gbNode, 1024, 0, stream>>>(epart2, bstart, cur, seg, v1, v0, dinv, z2, N);
        gather_seg<<<gbNode, 1024, 0, stream>>>(epart2, bstart, cur, seg, v0, v1, dinv, z3, N);
        if (fits) {
            gather_out_seg<<<gbNode, 1024, 0, stream>>>(epart2, bstart, v1, dinv,
                                                        z1, z2, z3, c, b4,
                                                        (float*)d_out, N);
        } else {
            gather_seg<<<gbNode, 1024, 0, stream>>>(epart2, bstart, cur, seg, v1, v0, dinv,
                                                    (float*)nullptr, N);
            write_out<<<(N * 32 + BLK - 1) / BLK, BLK, 0, stream>>>(
                v0, z1, z2, z3, dinv, c, b4, (float*)d_out, N);
        }
    }
}

// Round 14
// 385.688 us; speedup vs baseline: 2.7665x; 2.7665x over previous
//
#include <hip/hip_runtime.h>
#include <hip/hip_bf16.h>

// GCN 4-layer, linear network => collapse to:
// out = A^4 x0 * c4 + A^3 1 * c3 + A^2 1 * c2 + A 1 * c1 + b4,
// A = D^-1/2 (Adj+I) D^-1/2. Propagate in scaled space u' = D^-1 (Adj+I) u,
// epilogue multiplies sqrt(deg). Channels (x-path, ones-path) packed float2.
// Dtypes (R1-R4 verified): read_length int32, edge_index int32, W/b fp32, out fp32.
//
// R21: (a) REVERT R20's cooperative fusion: sweeps_coop = 883us vs 213 for
// split sweeps — grid.sync() costs O(100us) each on this stack (BW 0.36TB/s,
// VALU 4%: pure sync stall). Launch gaps are <=8us/dispatch — not worth
// structural surgery. Back to R18 (383us best). (b) Retry per-wave MLP=2 in
// the sweeps, done right this time: R19's arrays+unroll were re-rolled by
// the compiler (VGPR stayed 12 -> gathers serialized). Now straight-line
// NAMED scalars (nothing to re-roll) + sched_barrier(0) pinning both vin
// gathers before either scan consumes them -> gather-1's latency hides
// under scan-0's VALU work. Verification bit: sweep VGPR must rise >=20.

#define BLK  256
#define SBLK 1024         // scatter block
#define NB   512          // buckets
#define BSH  10           // bucket = dst >> 10  (1024 nodes / bucket)
#define PB   512          // partition blocks
#define BUFCAP 15872      // scatter LDS sort buffer (chunk = ceil(8M/512) = 15625)
#define BUF2 17920        // csr LDS buffer (bucket mean 16384, sd ~128; +12 sigma)
#define CAP  18432        // epart segment capacity per bucket (mean + 16 sigma)

// block 0: int64-layout probe (if rl were int64, every odd word is 0).
// block 1: zero the global bucket cursors.
__global__ void probe_i64(const int* __restrict__ rl32, int* __restrict__ flag,
                          int* __restrict__ cur) {
    __shared__ int sm[BLK];
    int t = threadIdx.x;
    if (blockIdx.x == 1) {
        for (int k = t; k < NB; k += BLK) cur[k] = 0;
        return;
    }
    int acc = 0;
    for (int k = t; k < 1024; k += blockDim.x)
        acc |= rl32[2 * k + 1];
    sm[t] = acc; __syncthreads();
    for (int off = BLK / 2; off > 0; off >>= 1) {
        if (t < off) sm[t] |= sm[t + off];
        __syncthreads();
    }
    if (t == 0) *flag = (sm[0] != 0) ? 1 : 0;   // 1 => int32 layout
}

// single-pass scatter: block-local LDS counting sort by bucket, one global
// atomicAdd per bucket run reserves space in the bucket's CAP segment; runs
// copied out dense+coalesced (lines written once, full).
__global__ __launch_bounds__(SBLK)
void scatter(const int* __restrict__ src, const int* __restrict__ dst,
             int* __restrict__ cur, unsigned* __restrict__ epart, int E) {
    __shared__ unsigned buf[BUFCAP];     // 62 KB
    __shared__ int h[NB];                // per-chunk counts
    __shared__ int c0[NB];               // fill cursor (exclusive starts)
    __shared__ int gpos[NB];             // reserved global position
    __shared__ int wsum[8];              // wave totals for scan
    int j = blockIdx.x, t = threadIdx.x;
    int lane = t & 63, w = t >> 6;
    int chunk = (E + PB - 1) / PB;
    int beg = j * chunk, end = min(beg + chunk, E);
    for (int s = beg; s < end; s += BUFCAP) {
        int se = min(s + BUFCAP, end);
        for (int b = t; b < NB; b += SBLK) h[b] = 0;
        __syncthreads();
        for (int e = s + t; e < se; e += SBLK)
            atomicAdd(&h[((unsigned)dst[e]) >> BSH], 1);
        __syncthreads();
        // hierarchical exclusive scan of h into c0 (512 entries, 8 waves)
        if (t < NB) {
            int v = h[t];
            int run = v;
#pragma unroll
            for (int off = 1; off < 64; off <<= 1) {
                int u = __shfl_up(run, off);
                if (lane >= off) run += u;
            }
            if (lane == 63) wsum[w] = run;
            c0[t] = run - v;             // intra-wave exclusive
        }
        __syncthreads();
        if (t < 8) {                     // scan 8 wave totals (one wave)
            int v = wsum[t];
            int run = v;
#pragma unroll
            for (int off = 1; off < 8; off <<= 1) {
                int u = __shfl_up(run, off, 8);
                if ((t & 7) >= off) run += u;
            }
            wsum[t] = run - v;           // exclusive wave offsets
        }
        __syncthreads();
        if (t < NB) c0[t] += wsum[w];
        __syncthreads();
        // fill LDS buffer sorted by bucket
        for (int e = s + t; e < se; e += SBLK) {
            unsigned d = (unsigned)dst[e];
            int b = d >> BSH;
            int slot = atomicAdd(&c0[b], 1);
            buf[slot] = ((d & 1023u) << 19) | (unsigned)src[e];
        }
        __syncthreads();
        // reserve global space: one thread per bucket
        if (t < NB) {
            int n = h[t];
            gpos[t] = (n > 0) ? atomicAdd(&cur[t], n) : 0;
        }
        __syncthreads();
        // copy out: wave w handles buckets w, w+16, ... (runs contiguous)
        for (int b = w; b < NB; b += (SBLK >> 6)) {
            int n = h[b];
            int lo = c0[b] - n;          // c0 back to inclusive after fill
            int gp = gpos[b];
            int left = CAP - gp;         // overflow guard (unreachable)
            if (left < 0) left = 0;
            if (n > left) n = left;
            unsigned gb = (unsigned)b * CAP + (unsigned)gp;
            for (int k = lane; k < n; k += 64)
                epart[gb + k] = buf[lo + k];
        }
        __syncthreads();
    }
}

// per-bucket dst-sort (keeps full pack) + compact write + bstart; node init
// fused (degree = pre-scan count); coeffs in the last block.
// seg=0: compact epart2 (disjoint). seg=1: sorted in place in the segment.
__global__ __launch_bounds__(1024)
void csr_init(const unsigned* __restrict__ epart, const int* __restrict__ cur,
              const int* __restrict__ rl, const int* __restrict__ flag,
              unsigned* __restrict__ epart2, int* __restrict__ bstart,
              float* __restrict__ dinv, float2* __restrict__ v0, int N,
              const float* __restrict__ W1, const float* __restrict__ b1,
              const float* __restrict__ W2, const float* __restrict__ b2,
              const float* __restrict__ W3, const float* __restrict__ b3,
              const float* __restrict__ W4, const float* __restrict__ b4,
              float* __restrict__ c, int seg) {
    __shared__ unsigned buf[BUF2];     // 70 KB
    __shared__ int sc[1024];           // histogram counts
    __shared__ int cu[1024];           // fill cursors (exclusive starts)
    __shared__ int wsum[16];
    __shared__ int s_beg, s_n;
    int b = blockIdx.x, t = threadIdx.x;
    if (b == gridDim.x - 1) {
        // coeffs block
        __shared__ float p3[16], q3[16], r3[16];
        if (t == 0) {
            float p2[8], q2[8];
            for (int j = 0; j < 8; ++j) {
                float s1 = 0.f, s2 = 0.f;
                for (int k = 0; k < 4; ++k) {
                    float w = W2[k * 8 + j];
                    s1 += W1[k] * w;
                    s2 += b1[k] * w;
                }
                p2[j] = s1; q2[j] = s2;
            }
            for (int m = 0; m < 16; ++m) {
                float s1 = 0.f, s2 = 0.f, s3 = 0.f;
                for (int j = 0; j < 8; ++j) {
                    float w = W3[j * 16 + m];
                    s1 += p2[j] * w; s2 += q2[j] * w;
                    s3 += b2[j] * w;
                }
                p3[m] = s1; q3[m] = s2; r3[m] = s3;
            }
        }
        __syncthreads();
        if (t < 32) {
            float c4 = 0.f, c3 = 0.f, c2 = 0.f, c1 = 0.f;
            for (int k = 0; k < 16; ++k) {
                float w = W4[k * 32 + t];
                c4 += p3[k] * w; c3 += q3[k] * w; c2 += r3[k] * w;
                c1 += b3[k] * w;
            }
            c[t] = c4; c[32 + t] = c3; c[64 + t] = c2; c[96 + t] = c1;
        }
        return;
    }
    int lane = t & 63, w = t >> 6;
    if (t < 64) {
        int pre = 0, nn = 0;
        for (int k = t; k < NB; k += 64) {
            int v = min(cur[k], CAP);
            if (k < b) pre += v;
            if (k == b) nn = v;
        }
        for (int off = 1; off < 64; off <<= 1) {
            pre += __shfl_xor(pre, off);
            nn  += __shfl_xor(nn, off);
        }
        if (t == 0) { s_beg = pre; s_n = nn; }
    }
    sc[t] = 0;
    __syncthreads();
    int n = s_n;
    int gseg = b * CAP;
    int beg = seg ? gseg : s_beg;
    if (t == 0) bstart[b] = beg;
    if (b == gridDim.x - 2 && t == 1) bstart[b + 1] = beg + n;
    for (int e = t; e < n; e += 1024)
        atomicAdd(&sc[epart[gseg + e] >> 19], 1);
    __syncthreads();
    // hierarchical inclusive scan of sc (1024 entries, 16 waves)
    int v = sc[t];
    int run = v;
#pragma unroll
    for (int off = 1; off < 64; off <<= 1) {
        int u = __shfl_up(run, off);
        if (lane >= off) run += u;
    }
    if (lane == 63) wsum[w] = run;
    __syncthreads();
    if (t < 16) {
        int vv = wsum[t];
        int r2 = vv;
#pragma unroll
        for (int off = 1; off < 16; off <<= 1) {
            int u = __shfl_up(r2, off, 16);
            if ((t & 15) >= off) r2 += u;
        }
        wsum[t] = r2 - vv;               // exclusive wave offsets
    }
    __syncthreads();
    int incl = run + wsum[w];            // inclusive prefix incl. own count
    int start = incl - v;                // exclusive, bucket-local slot
    cu[t] = start;
    // fused node init: degree = v (own count)
    int gi = (b << 10) + t;
    if (gi < N) {
        int rv = (*flag) ? rl[gi] : rl[2 * gi];
        float d = (float)v + 1.0f;       // + self-loop
        dinv[gi] = 1.0f / d;
        float rs = rsqrtf(d);
        float2 u; u.x = rs * ((float)rv * (1.0f / 20000.0f)); u.y = rs;
        v0[gi] = u;
    }
    __syncthreads();
    if (n <= BUF2) {
        for (int e = t; e < n; e += 1024) {
            unsigned p = epart[gseg + e];
            int slot = atomicAdd(&cu[p >> 19], 1);
            buf[slot] = p;               // FULL pack (dst|src) kept
        }
        __syncthreads();
        for (int k = t; k < n; k += 1024)
            epart2[beg + k] = buf[k];    // dense coalesced write-out
    } else if (!seg) {
        for (int e = t; e < n; e += 1024) {
            unsigned p = epart[gseg + e];
            int slot = atomicAdd(&cu[p >> 19], 1);
            epart2[beg + slot] = p;
        }
    }
    // seg && n>BUF2: unreachable (P ~ 1e-33).
}

// R21 sweep: block per bucket; per iteration, TWO 64-edge windows as
// straight-line named scalars — both vin gathers issued before either scan
// (sched_barrier(0) pins order) -> MLP=2, gather-1 latency hides under
// scan-0 VALU work. Row-16 DPP segmented scan + LDS atomicAdd at tails.
__global__ __launch_bounds__(1024)
void gather_seg(const unsigned* __restrict__ ep, const int* __restrict__ bstart,
                const int* __restrict__ cur, int seg,
                const float2* __restrict__ vin, float2* __restrict__ vout,
                const float* __restrict__ dinv, float* __restrict__ zsave, int N) {
    __shared__ float ax[1024];
    __shared__ float ay[1024];
    int b = blockIdx.x, t = threadIdx.x;
    ax[t] = 0.f; ay[t] = 0.f;
    __syncthreads();
    int beg = bstart[b];
    int n = seg ? min(cur[b], CAP) : (bstart[b + 1] - beg);
    int end = beg + n;
    int lane = t & 63, sub = lane & 15;
    for (int base = beg + (t - lane); base < end; base += 2048) {
        int e0 = base + lane;
        int e1 = base + 1024 + lane;
        unsigned p0 = (e0 < end) ? ep[e0] : 0xFFFFFFFFu;  // sentinel key 8191
        unsigned p1 = (e1 < end) ? ep[e1] : 0xFFFFFFFFu;
        float v0x = 0.f, v0y = 0.f, v1x = 0.f, v1y = 0.f;
        if (p0 != 0xFFFFFFFFu) {
            float2 u = vin[p0 & 0x7FFFFu];
            v0x = u.x; v0y = u.y;
        }
        if (p1 != 0xFFFFFFFFu) {
            float2 u = vin[p1 & 0x7FFFFu];
            v1x = u.x; v1y = u.y;
        }
        __builtin_amdgcn_sched_barrier(0);   // both gathers issued before scans
        {   // scan window 0
            int key = (int)(p0 >> 19);
            float sx = v0x, sy = v0y;
#pragma unroll
            for (int off = 1; off < 16; off <<= 1) {     // row-16 DPP scan
                float ox = __shfl_up(sx, off, 16);
                float oy = __shfl_up(sy, off, 16);
                int ok = __shfl_up(key, off, 16);
                bool act = (sub >= off) && (ok == key);
                sx += act ? ox : 0.f;
                sy += act ? oy : 0.f;
            }
            int nk = __shfl_down(key, 1);
            bool tail = (sub == 15) || (lane == 63) || (nk != key);
            if (tail && key < 1024) {
                atomicAdd(&ax[key], sx);
                atomicAdd(&ay[key], sy);
            }
        }
        {   // scan window 1
            int key = (int)(p1 >> 19);
            float sx = v1x, sy = v1y;
#pragma unroll
            for (int off = 1; off < 16; off <<= 1) {     // row-16 DPP scan
                float ox = __shfl_up(sx, off, 16);
                float oy = __shfl_up(sy, off, 16);
                int ok = __shfl_up(key, off, 16);
                bool act = (sub >= off) && (ok == key);
                sx += act ? ox : 0.f;
                sy += act ? oy : 0.f;
            }
            int nk = __shfl_down(key, 1);
            bool tail = (sub == 15) || (lane == 63) || (nk != key);
            if (tail && key < 1024) {
                atomicAdd(&ax[key], sx);
                atomicAdd(&ay[key], sy);
            }
        }
    }
    __syncthreads();
    int gi = (b << 10) + t;
    if (gi < N) {
        float2 self = vin[gi];
        float di = dinv[gi];
        float2 o; o.x = (ax[t] + self.x) * di; o.y = (ay[t] + self.y) * di;
        vout[gi] = o;
        if (zsave) zsave[gi] = o.y;
    }
}

// R21 fused final sweep + epilogue (x-channel only), 2-deep pipelined. After
// accumulation, finalized ox and sqrt(deg) republished in LDS; epilogue
// channel-parallel (32 threads/node) for coalesced 128B stores. Valid only
// when epart2 is in workspace (out aliases d_out).
__global__ __launch_bounds__(1024)
void gather_out_seg(const unsigned* __restrict__ ep, const int* __restrict__ bstart,
                    const float2* __restrict__ vin, const float* __restrict__ dinv,
                    const float* __restrict__ z1, const float* __restrict__ z2,
                    const float* __restrict__ z3, const float* __restrict__ c,
                    const float* __restrict__ b4, float* __restrict__ out, int N) {
    __shared__ float ax[1024];
    __shared__ float sqs[1024];
    int b = blockIdx.x, t = threadIdx.x;
    ax[t] = 0.f;
    __syncthreads();
    int beg = bstart[b], end = bstart[b + 1];
    int lane = t & 63, sub = lane & 15;
    for (int base = beg + (t - lane); base < end; base += 2048) {
        int e0 = base + lane;
        int e1 = base + 1024 + lane;
        unsigned p0 = (e0 < end) ? ep[e0] : 0xFFFFFFFFu;
        unsigned p1 = (e1 < end) ? ep[e1] : 0xFFFFFFFFu;
        float v0x = 0.f, v1x = 0.f;
        if (p0 != 0xFFFFFFFFu) v0x = vin[p0 & 0x7FFFFu].x;
        if (p1 != 0xFFFFFFFFu) v1x = vin[p1 & 0x7FFFFu].x;
        __builtin_amdgcn_sched_barrier(0);
        {   // scan window 0
            int key = (int)(p0 >> 19);
            float sx = v0x;
#pragma unroll
            for (int off = 1; off < 16; off <<= 1) {     // row-16 DPP scan
                float ox = __shfl_up(sx, off, 16);
                int ok = __shfl_up(key, off, 16);
                bool act = (sub >= off) && (ok == key);
                sx += act ? ox : 0.f;
            }
            int nk = __shfl_down(key, 1);
            bool tail = (sub == 15) || (lane == 63) || (nk != key);
            if (tail && key < 1024) atomicAdd(&ax[key], sx);
        }
        {   // scan window 1
            int key = (int)(p1 >> 19);
            float sx = v1x;
#pragma unroll
            for (int off = 1; off < 16; off <<= 1) {     // row-16 DPP scan
                float ox = __shfl_up(sx, off, 16);
                int ok = __shfl_up(key, off, 16);
                bool act = (sub >= off) && (ok == key);
                sx += act ? ox : 0.f;
            }
            int nk = __shfl_down(key, 1);
            bool tail = (sub == 15) || (lane == 63) || (nk != key);
            if (tail && key < 1024) atomicAdd(&ax[key], sx);
        }
    }
    __syncthreads();
    int gi = (b << 10) + t;
    float ox = 0.f, sq = 0.f;
    if (gi < N) {
        float di = dinv[gi];
        ox = (ax[t] + vin[gi].x) * di;   // final A^4 x (scaled space)
        sq = rsqrtf(di);                 // = sqrt(deg)
    }
    __syncthreads();
    ax[t] = ox; sqs[t] = sq;             // own slot only
    __syncthreads();
    // channel-parallel epilogue
    int f = t & 31, half = t >> 5;       // half in [0,32)
    float c4 = c[f], c3 = c[32 + f], c2 = c[64 + f], c1 = c[96 + f], bb = b4[f];
    int base_node = b << 10;
    for (int p = 0; p < 32; ++p) {
        int ln = p * 32 + half;
        int g = base_node + ln;
        if (g < N) {
            float zz1 = z1[g], zz2 = z2[g], zz3 = z3[g];
            float val = sqs[ln] * (ax[ln] * c4 + zz3 * c3 + zz2 * c2 + zz1 * c1) + bb;
            out[(size_t)g * 32 + f] = val;
        }
    }
}

// fallback epilogue (split path)
__global__ void write_out(const float2* __restrict__ v0, const float* __restrict__ z1,
                          const float* __restrict__ z2, const float* __restrict__ z3,
                          const float* __restrict__ dinv, const float* __restrict__ c,
                          const float* __restrict__ b4,
                          float* __restrict__ out, int N) {
    int t = blockIdx.x * blockDim.x + threadIdx.x;
    int i = t >> 5, f = t & 31;
    if (i < N) {
        float sq = rsqrtf(dinv[i]);  // = sqrt(deg)
        float v = sq * (v0[i].x * c[f] + z3[i] * c[32 + f] + z2[i] * c[64 + f]
                        + z1[i] * c[96 + f])
                  + b4[f];
        out[(size_t)i * 32 + f] = v;
    }
}

extern "C" void kernel_launch(void* const* d_in, const int* in_sizes, int n_in,
                              void* d_out, int out_size, void* d_ws, size_t ws_size,
                              hipStream_t stream) {
    const int N = in_sizes[0];
    const int E = in_sizes[1] / 2;
    const int* rl  = (const int*)d_in[0];
    const int* src = (const int*)d_in[1];
    const int* dst = src + E;
    const float* W1 = (const float*)d_in[2];
    const float* b1 = (const float*)d_in[3];
    const float* W2 = (const float*)d_in[4];
    const float* b2 = (const float*)d_in[5];
    const float* W3 = (const float*)d_in[6];
    const float* b3 = (const float*)d_in[7];
    const float* W4 = (const float*)d_in[8];
    const float* b4 = (const float*)d_in[9];

    const int gbNode = (N + 1023) / 1024;     // buckets containing nodes (489)

    // workspace layout
    char* w = (char*)d_ws;
    float2* v0   = (float2*)w;                w += (size_t)N * 8;
    float2* v1   = (float2*)w;                w += (size_t)N * 8;
    float*  dinv = (float*)w;                 w += (size_t)N * 4;
    float*  z1   = (float*)w;                 w += (size_t)N * 4;
    float*  z2   = (float*)w;                 w += (size_t)N * 4;
    float*  z3   = (float*)w;                 w += (size_t)N * 4;
    int*    bstart = (int*)w;                 w += (NB + 1) * 4;
    int*    cur  = (int*)w;                   w += NB * 4;
    float*  c    = (float*)w;                 w += 128 * 4;
    int*    flag = (int*)w;                   w += 16;
    // epart2 (compact, dst-sorted) in workspace if it fits
    size_t used = (size_t)(w - (char*)d_ws);
    used = (used + 255) & ~(size_t)255;
    bool fits = (used + (size_t)E * 4) <= ws_size;
    // segmented epart always lives in d_out (NB*CAP*4 = 37.75 MB <= 64 MB)
    unsigned* epart  = (unsigned*)d_out;
    unsigned* epart2 = fits ? (unsigned*)((char*)d_ws + used) : epart;  // in-place if !fits
    const int seg = fits ? 0 : 1;

    probe_i64<<<2, BLK, 0, stream>>>(rl, flag, cur);

    // single-pass radix partition by dst bucket (atomic segment reservation)
    scatter<<<PB, SBLK, 0, stream>>>(src, dst, cur, epart, E);

    // within-bucket dst-sort + bstart + fused node init + coeffs
    csr_init<<<gbNode + 1, 1024, 0, stream>>>(epart, cur, rl, flag, epart2, bstart,
                                              dinv, v0, N,
                                              W1, b1, W2, b2, W3, b3, W4, b4, c, seg);

    // 4 propagation sweeps, ping-pong v0<->v1 (2-deep pipelined row-16 scan)
    gather_seg<<<gbNode, 1024, 0, stream>>>(epart2, bstart, cur, seg, v0, v1, dinv, z1, N);
    gather_seg<<<gbNode, 1024, 0, stream>>>(epart2, bstart, cur, seg, v1, v0, dinv, z2, N);
    gather_seg<<<gbNode, 1024, 0, stream>>>(epart2, bstart, cur, seg, v0, v1, dinv, z3, N);
    if (fits) {
        gather_out_seg<<<gbNode, 1024, 0, stream>>>(epart2, bstart, v1, dinv,
                                                    z1, z2, z3, c, b4,
                                                    (float*)d_out, N);
    } else {
        gather_seg<<<gbNode, 1024, 0, stream>>>(epart2, bstart, cur, seg, v1, v0, dinv,
                                                (float*)nullptr, N);
        write_out<<<(N * 32 + BLK - 1) / BLK, BLK, 0, stream>>>(
            v0, z1, z2, z3, dinv, c, b4, (float*)d_out, N);
    }
}